// Round 4
// baseline (5396.283 us; speedup 1.0000x reference)
//
#include <hip/hip_runtime.h>

#define NN 64
#define NI 6
#define TT 1024
#define BB 1024
#define TB (TT * BB)
#define NSCALE 0.13416407864998738f        // sqrt(2/alpha) * sigma
#define ARNSCALE 0.013416407864998739f     // alpha * NSCALE

typedef __attribute__((ext_vector_type(8))) short bf16x8;
typedef __attribute__((ext_vector_type(16))) float f32x16;
typedef __attribute__((ext_vector_type(4))) unsigned int u32x4;
typedef __attribute__((ext_vector_type(2))) unsigned int u32x2;

__device__ __forceinline__ bf16x8 asb(u32x4 v) {
    union { u32x4 u; bf16x8 b; } c; c.u = v; return c.b;
}

__device__ __forceinline__ unsigned pkbf(float a, float b) {  // lo16=bf16(a), hi16=bf16(b)
    unsigned r;
    asm("v_cvt_pk_bf16_f32 %0, %1, %2" : "=v"(r) : "v"(a), "v"(b));
    return r;
}

// split (x0,x1) into hi word (truncated bf16 pair) + lo word (bf16 of residual)
__device__ __forceinline__ void split2(float x0, float x1, unsigned &hw, unsigned &lw) {
    unsigned h0 = __float_as_uint(x0) & 0xFFFF0000u;
    unsigned h1 = __float_as_uint(x1) & 0xFFFF0000u;
    float l0 = x0 - __uint_as_float(h0);
    float l1 = x1 - __uint_as_float(h1);
    hw = h1 | (h0 >> 16);
    lw = pkbf(l0, l1);
}

#define MFMA(A, B, C) __builtin_amdgcn_mfma_f32_32x32x16_bf16(asb(A), asb(B), (C), 0, 0, 0)

// 32 blocks x 64 threads. Wave = 32 batches (col=lane&31), per-step 64x64x64 GEMM on MFMA.
// D[n][b] = Wrec·x^T + Winp·(u+c·inn)^T ; C/D: col=lane&31=b, row n=(r&3)+8(r>>2)+4(lane>>5).
__global__ __launch_bounds__(64, 1) void latent_rnn_mfma(
    const float* __restrict__ u,      // (6, T, B)
    const float* __restrict__ rn,     // (64, T, B)
    const float* __restrict__ inn,    // (6, T, B)
    const float* __restrict__ Winp,   // (64, 6)
    const float* __restrict__ Wrec,   // (64, 64)
    float* __restrict__ states)       // (64, T, B)
{
    const int lane = threadIdx.x;
    const int col  = lane & 31;
    const int H    = lane >> 5;
    const int b0   = blockIdx.x * 32;

    // element offsets (n*TB + b) for rn loads / states stores, per (mt, reg)
    int off[2][16];
#pragma unroll
    for (int mt = 0; mt < 2; ++mt)
#pragma unroll
        for (int r = 0; r < 16; ++r) {
            int n = 32 * mt + (r & 3) + 8 * (r >> 2) + 4 * H;
            off[mt][r] = n * TB + b0 + col;
        }
    int uoff[6];
#pragma unroll
    for (int e = 0; e < NI; ++e) uoff[e] = e * TB + b0 + col;

    // ---- Wrec A-fragments (hi/lo split), constant: A[m][k], m=col+32mt, k=16kk+8H+e ----
    u32x4 WAh[2][4], WAl[2][4];
#pragma unroll
    for (int mt = 0; mt < 2; ++mt)
#pragma unroll
        for (int kk = 0; kk < 4; ++kk) {
            const float* wp = Wrec + (col + 32 * mt) * NN + 16 * kk + 8 * H;
            float4 wa = *reinterpret_cast<const float4*>(wp);
            float4 wb = *reinterpret_cast<const float4*>(wp + 4);
            float w[8] = {wa.x, wa.y, wa.z, wa.w, wb.x, wb.y, wb.z, wb.w};
            u32x4 hv, lv;
#pragma unroll
            for (int p = 0; p < 4; ++p) {
                unsigned hh, ll; split2(w[2*p], w[2*p+1], hh, ll);
                hv[p] = hh; lv[p] = ll;
            }
            WAh[mt][kk] = hv; WAl[mt][kk] = lv;
        }

    // ---- Winp A-fragments (K=16 block, k=8H+e: H=1 rows are zero pad) ----
    u32x4 IAh[2], IAl[2];
#pragma unroll
    for (int mt = 0; mt < 2; ++mt) {
        float w[8];
#pragma unroll
        for (int e = 0; e < 8; ++e)
            w[e] = (H == 0 && e < NI) ? Winp[(col + 32 * mt) * NI + e] : 0.0f;
        u32x4 hv, lv;
#pragma unroll
        for (int p = 0; p < 4; ++p) {
            unsigned hh, ll; split2(w[2*p], w[2*p+1], hh, ll);
            hv[p] = hh; lv[p] = ll;
        }
        IAh[mt] = hv; IAl[mt] = lv;
    }

    // ---- state + x B-fragments start at zero ----
    float xx[2][16];
#pragma unroll
    for (int mt = 0; mt < 2; ++mt)
#pragma unroll
        for (int r = 0; r < 16; ++r) xx[mt][r] = 0.0f;
    u32x4 Bxh[4], Bxl[4];
#pragma unroll
    for (int kk = 0; kk < 4; ++kk) { Bxh[kk] = (u32x4)(0u); Bxl[kk] = (u32x4)(0u); }

    // states t=0 row = 0
#pragma unroll
    for (int mt = 0; mt < 2; ++mt)
#pragma unroll
        for (int r = 0; r < 16; ++r) states[off[mt][r]] = 0.0f;

    // ---- prefetch steps 0 and 1 ----
    float RA[2][16], RB[2][16], UA[12], UB[12];
    {
        const float* rp = rn; const float* up = u; const float* ip = inn;
#pragma unroll
        for (int mt = 0; mt < 2; ++mt)
#pragma unroll
            for (int r = 0; r < 16; ++r) { RA[mt][r] = rp[off[mt][r]]; RB[mt][r] = rp[BB + off[mt][r]]; }
#pragma unroll
        for (int e = 0; e < NI; ++e) {
            UA[e] = up[uoff[e]];        UA[6 + e] = ip[uoff[e]];
            UB[e] = up[BB + uoff[e]];   UB[6 + e] = ip[BB + uoff[e]];
        }
    }

    const f32x16 Z = (f32x16)(0.0f);

#define STEP(tcur, RNB, UIB)                                                    \
  {                                                                             \
    /* input B-frags (hi/lo); zero for H=1 lanes (pad rows k=8..15) */          \
    unsigned ibh[3], ibl[3];                                                    \
    _Pragma("unroll")                                                           \
    for (int p = 0; p < 3; ++p) {                                               \
        float e0 = fmaf(NSCALE, UIB[6 + 2*p], UIB[2*p]);                        \
        float e1 = fmaf(NSCALE, UIB[7 + 2*p], UIB[1 + 2*p]);                    \
        split2(e0, e1, ibh[p], ibl[p]);                                         \
    }                                                                           \
    if (H) { ibh[0]=ibh[1]=ibh[2]=0u; ibl[0]=ibl[1]=ibl[2]=0u; }                \
    const u32x4 BIH = (u32x4){ibh[0], ibh[1], ibh[2], 0u};                      \
    const u32x4 BIL = (u32x4){ibl[0], ibl[1], ibl[2], 0u};                      \
    /* tbase = 0.9x + ARN*rn : independent of D, hides under MFMA */            \
    float tb[2][16];                                                            \
    _Pragma("unroll")                                                           \
    for (int mt = 0; mt < 2; ++mt)                                              \
        _Pragma("unroll")                                                       \
        for (int r = 0; r < 16; ++r)                                            \
            tb[mt][r] = fmaf(0.9f, xx[mt][r], ARNSCALE * RNB[mt][r]);           \
    /* prefetch t+2 into the buffers just consumed */                           \
    {                                                                           \
        int tp = (tcur) + 2; if (tp > TT - 2) tp = TT - 2;                      \
        const float* rp = rn + tp * BB;                                         \
        const float* up = u + tp * BB;                                          \
        const float* ip = inn + tp * BB;                                        \
        _Pragma("unroll")                                                       \
        for (int mt = 0; mt < 2; ++mt)                                          \
            _Pragma("unroll")                                                   \
            for (int r = 0; r < 16; ++r) RNB[mt][r] = rp[off[mt][r]];           \
        _Pragma("unroll")                                                       \
        for (int e = 0; e < NI; ++e) { UIB[e] = up[uoff[e]]; UIB[6+e] = ip[uoff[e]]; } \
    }                                                                           \
    /* MFMA chains: input term + 3-way split product over 4 K-blocks */        \
    f32x16 D0 = MFMA(IAh[0], BIH, Z);                                           \
    D0 = MFMA(IAh[0], BIL, D0);                                                 \
    D0 = MFMA(IAl[0], BIH, D0);                                                 \
    f32x16 D1 = MFMA(IAh[1], BIH, Z);                                           \
    D1 = MFMA(IAh[1], BIL, D1);                                                 \
    D1 = MFMA(IAl[1], BIH, D1);                                                 \
    _Pragma("unroll")                                                           \
    for (int kk = 0; kk < 4; ++kk) {                                            \
        D0 = MFMA(WAh[0][kk], Bxh[kk], D0);                                     \
        D0 = MFMA(WAh[0][kk], Bxl[kk], D0);                                     \
        D0 = MFMA(WAl[0][kk], Bxh[kk], D0);                                     \
        D1 = MFMA(WAh[1][kk], Bxh[kk], D1);                                     \
        D1 = MFMA(WAh[1][kk], Bxl[kk], D1);                                     \
        D1 = MFMA(WAl[1][kk], Bxh[kk], D1);                                     \
    }                                                                           \
    /* update + coalesced store */                                              \
    float* sp = states + ((tcur) + 1) * BB;                                     \
    _Pragma("unroll")                                                           \
    for (int mt = 0; mt < 2; ++mt)                                              \
        _Pragma("unroll")                                                       \
        for (int r = 0; r < 16; ++r) {                                          \
            float d  = (mt == 0) ? D0[r] : D1[r];                               \
            float xn = fmaf(0.1f, fmaxf(d, 0.0f), tb[mt][r]);                   \
            xx[mt][r] = xn;                                                     \
            sp[off[mt][r]] = xn;                                                \
        }                                                                       \
    /* repack x into B-frags for next step: 4 splits + 4 permlane32_swap / K-block */ \
    _Pragma("unroll")                                                           \
    for (int kk = 0; kk < 4; ++kk) {                                            \
        const int mtp = kk >> 1, rb = (kk & 1) * 8;                             \
        unsigned ah, al, bh_, bl_, ch, cl, dh, dl;                              \
        split2(xx[mtp][rb+0], xx[mtp][rb+1], ah, al);                           \
        split2(xx[mtp][rb+2], xx[mtp][rb+3], bh_, bl_);                         \
        split2(xx[mtp][rb+4], xx[mtp][rb+5], ch, cl);                           \
        split2(xx[mtp][rb+6], xx[mtp][rb+7], dh, dl);                           \
        u32x2 s0 = __builtin_amdgcn_permlane32_swap(ah,  ch, false, false);     \
        u32x2 s1 = __builtin_amdgcn_permlane32_swap(bh_, dh, false, false);     \
        u32x2 s2 = __builtin_amdgcn_permlane32_swap(al,  cl, false, false);     \
        u32x2 s3 = __builtin_amdgcn_permlane32_swap(bl_, dl, false, false);     \
        Bxh[kk] = (u32x4){s0.x, s1.x, s0.y, s1.y};                              \
        Bxl[kk] = (u32x4){s2.x, s3.x, s2.y, s3.y};                              \
    }                                                                           \
  }

#pragma unroll 1
    for (int t = 0; t < TT - 2; t += 2) {   // steps 0..1021
        STEP(t,     RA, UA);
        STEP(t + 1, RB, UB);
    }
    STEP(TT - 2, RA, UA);                   // step 1022
#undef STEP
}

// outputs = states @ Wout^T : pure streaming pass (268 MB read, 8 MB write)
__global__ __launch_bounds__(256) void out_proj(
    const float* __restrict__ states,   // (64, T*B)
    const float* __restrict__ Wout,     // (2, 64)
    float* __restrict__ outputs)        // (2, T*B)
{
    const int g4 = (blockIdx.x * 256 + threadIdx.x) * 4;
    float4 a0 = {0.f, 0.f, 0.f, 0.f};
    float4 a1 = {0.f, 0.f, 0.f, 0.f};
#pragma unroll
    for (int k = 0; k < NN; ++k) {
        const float4 s = *reinterpret_cast<const float4*>(states + k * TB + g4);
        const float w0 = Wout[k];
        const float w1 = Wout[NN + k];
        a0.x = fmaf(s.x, w0, a0.x); a0.y = fmaf(s.y, w0, a0.y);
        a0.z = fmaf(s.z, w0, a0.z); a0.w = fmaf(s.w, w0, a0.w);
        a1.x = fmaf(s.x, w1, a1.x); a1.y = fmaf(s.y, w1, a1.y);
        a1.z = fmaf(s.z, w1, a1.z); a1.w = fmaf(s.w, w1, a1.w);
    }
    *reinterpret_cast<float4*>(outputs + g4)      = a0;
    *reinterpret_cast<float4*>(outputs + TB + g4) = a1;
}

extern "C" void kernel_launch(void* const* d_in, const int* in_sizes, int n_in,
                              void* d_out, int out_size, void* d_ws, size_t ws_size,
                              hipStream_t stream) {
    const float* u    = (const float*)d_in[0];
    const float* rn   = (const float*)d_in[1];
    const float* inn  = (const float*)d_in[2];
    const float* Winp = (const float*)d_in[3];
    const float* Wrec = (const float*)d_in[4];
    const float* Wout = (const float*)d_in[5];

    float* states  = (float*)d_out;                          // 64*1024*1024
    float* outputs = (float*)d_out + (size_t)NN * TT * BB;   // 2*1024*1024

    latent_rnn_mfma<<<32, 64, 0, stream>>>(u, rn, inn, Winp, Wrec, states);
    out_proj<<<1024, 256, 0, stream>>>(states, Wout, outputs);
}

// Round 5
// 706.261 us; speedup vs baseline: 7.6406x; 7.6406x over previous
//
#include <hip/hip_runtime.h>

#define NN 64
#define NI 6
#define TT 1024
#define BB 1024
#define TB (TT * BB)
#define NSCALE 0.13416407864998738f        // sqrt(2/alpha) * sigma
#define ARNSCALE 0.013416407864998739f     // alpha * NSCALE
#define SW 68   // wlds row stride (words): rows 16B-aligned, 2-way banks (free)
#define SX 72   // xb row stride (words): x[0..63], input-term[64..69], pad[70..71]

// Raw barrier: LDS-ordering only. NO vmcnt drain -> global prefetches stay in
// flight across the per-step barrier (round-1's poison removed).
#define BARRIER() do {                                                        \
    __builtin_amdgcn_sched_barrier(0);                                        \
    asm volatile("s_waitcnt lgkmcnt(0)\n\ts_barrier" ::: "memory");           \
    __builtin_amdgcn_sched_barrier(0);                                        \
} while (0)

// 256 blocks x 256 threads; thread = (n, b): n = tid>>2 (neuron), b = tid&3.
// 4 batches/block -> 16B-granule coalescing on rn/u/inn/states (16 lines/instr).
// x-exchange via double-buffered LDS row; W_rec row held in 64 VGPRs.
__global__ __launch_bounds__(256, 1) void latent_rnn(
    const float* __restrict__ u,      // (6, T, B)
    const float* __restrict__ rn,     // (64, T, B)
    const float* __restrict__ inn,    // (6, T, B)
    const float* __restrict__ Winp,   // (64, 6)
    const float* __restrict__ Wrec,   // (64, 64)
    float* __restrict__ states)       // (64, T, B)
{
    // XCD swizzle: 256 blocks, 32 consecutive logical blocks (=128 batches)/XCD
    const int hw  = blockIdx.x;
    const int lb  = (hw & 7) * 32 + (hw >> 3);
    const int b0  = lb * 4;
    const int tid = threadIdx.x;
    const int n   = tid >> 2;
    const int b   = tid & 3;
    const int gb  = b0 + b;

    __shared__ __align__(16) float wlds[NN * SW];
    __shared__ __align__(16) float xb[2][4][SX];

    // ---- Wrec -> LDS (coalesced 16B loads) ----
    {
        const float4* src = (const float4*)Wrec;   // 1024 float4s
#pragma unroll
        for (int j = 0; j < 4; ++j) {
            const int f4   = tid * 4 + j;
            const int flat = f4 * 4;
            *(float4*)&wlds[(flat >> 6) * SW + (flat & 63)] = src[f4];
        }
    }

    float wi[NI];
#pragma unroll
    for (int i = 0; i < NI; ++i) wi[i] = Winp[n * NI + i];

    // ---- init x buffers + t=0 input slots + states row 0 ----
    xb[0][b][n] = 0.0f;
    xb[1][b][n] = 0.0f;

    const bool stage = (tid < NI * 4);             // these threads have n = i < 6
    const float* usrc = u   + n * TB + gb;         // only deref'd when stage
    const float* isrc = inn + n * TB + gb;
    float su0 = 0.f, su1 = 0.f, si0 = 0.f, si1 = 0.f;
    if (stage) {
        xb[0][b][64 + n] = fmaf(NSCALE, isrc[0], usrc[0]);   // step-0 input term
        su1 = usrc[1 * BB]; si1 = isrc[1 * BB];              // step 1
        su0 = usrc[2 * BB]; si0 = isrc[2 * BB];              // step 2
    }

    states[n * TB + gb] = 0.0f;

    __syncthreads();   // once, pre-loop: init visible everywhere

    // ---- hoist W row to registers (asm-clobber barriers in the loop make
    //      re-materialization from LDS illegal -> stays in VGPRs) ----
    float wreg[NN];
    {
        const float4* wrow = (const float4*)&wlds[n * SW];
#pragma unroll
        for (int k4 = 0; k4 < 16; ++k4) {
            const float4 wv = wrow[k4];
            wreg[4*k4+0] = wv.x; wreg[4*k4+1] = wv.y;
            wreg[4*k4+2] = wv.z; wreg[4*k4+3] = wv.w;
        }
    }

    const float* rsrc = rn + n * TB + gb;
    float* sdst = states + n * TB + gb;

    // rn prefetch ring, depth 4, static slots
    float rnb[4];
#pragma unroll
    for (int d = 0; d < 4; ++d) rnb[d] = rsrc[d * BB];

    float xreg = 0.0f;

#define STEP(tcur, slot, CC, SS)                                              \
  {                                                                           \
    const float rcur = rnb[slot];                                             \
    { int tp = (tcur) + 4; if (tp > TT - 1) tp = TT - 1;                      \
      rnb[slot] = rsrc[tp * BB]; }                                            \
    const float4* xrow = (const float4*)&xb[CC][b][0];                        \
    float a0 = 0.f, a1 = 0.f, a2 = 0.f, a3 = 0.f;                             \
    _Pragma("unroll")                                                         \
    for (int k4 = 0; k4 < 16; ++k4) {                                         \
        const float4 xv = xrow[k4];                                           \
        a0 = fmaf(xv.x, wreg[4*k4+0], a0);                                    \
        a1 = fmaf(xv.y, wreg[4*k4+1], a1);                                    \
        a2 = fmaf(xv.z, wreg[4*k4+2], a2);                                    \
        a3 = fmaf(xv.w, wreg[4*k4+3], a3);                                    \
    }                                                                         \
    const float4 iv0 = xrow[16];                                              \
    const float4 iv1 = xrow[17];                                              \
    a0 = fmaf(iv0.x, wi[0], a0); a1 = fmaf(iv0.y, wi[1], a1);                 \
    a2 = fmaf(iv0.z, wi[2], a2); a3 = fmaf(iv0.w, wi[3], a3);                 \
    a0 = fmaf(iv1.x, wi[4], a0); a1 = fmaf(iv1.y, wi[5], a1);                 \
    const float pre = (a0 + a1) + (a2 + a3);                                  \
    const float xn  = fmaf(0.9f, xreg,                                        \
                           fmaf(0.1f, fmaxf(pre, 0.f), ARNSCALE * rcur));     \
    xreg = xn;                                                                \
    sdst[((tcur) + 1) * BB] = xn;                                             \
    xb[(CC) ^ 1][b][n] = xn;                                                  \
    if (stage) {                                                              \
        xb[(CC) ^ 1][b][64 + n] =                                             \
            fmaf(NSCALE, (SS) ? si1 : si0, (SS) ? su1 : su0);                 \
        int tp3 = (tcur) + 3; if (tp3 > TT - 1) tp3 = TT - 1;                 \
        if (SS) { su1 = usrc[tp3 * BB]; si1 = isrc[tp3 * BB]; }               \
        else    { su0 = usrc[tp3 * BB]; si0 = isrc[tp3 * BB]; }               \
    }                                                                         \
    BARRIER();                                                                \
  }

#pragma unroll 1
    for (int t = 0; t < 1020; t += 4) {
        STEP(t + 0, 0, 0, 1);
        STEP(t + 1, 1, 1, 0);
        STEP(t + 2, 2, 0, 1);
        STEP(t + 3, 3, 1, 0);
    }
    STEP(1020, 0, 0, 1);
    STEP(1021, 1, 1, 0);
    STEP(1022, 2, 0, 1);
#undef STEP
}

// outputs = states @ Wout^T : streaming pass (268 MB read, 8 MB write)
__global__ __launch_bounds__(256) void out_proj(
    const float* __restrict__ states,   // (64, T*B)
    const float* __restrict__ Wout,     // (2, 64)
    float* __restrict__ outputs)        // (2, T*B)
{
    const int g4 = (blockIdx.x * 256 + threadIdx.x) * 4;
    float4 a0 = {0.f, 0.f, 0.f, 0.f};
    float4 a1 = {0.f, 0.f, 0.f, 0.f};
#pragma unroll
    for (int k = 0; k < NN; ++k) {
        const float4 s = *reinterpret_cast<const float4*>(states + k * TB + g4);
        const float w0 = Wout[k];
        const float w1 = Wout[NN + k];
        a0.x = fmaf(s.x, w0, a0.x); a0.y = fmaf(s.y, w0, a0.y);
        a0.z = fmaf(s.z, w0, a0.z); a0.w = fmaf(s.w, w0, a0.w);
        a1.x = fmaf(s.x, w1, a1.x); a1.y = fmaf(s.y, w1, a1.y);
        a1.z = fmaf(s.z, w1, a1.z); a1.w = fmaf(s.w, w1, a1.w);
    }
    *reinterpret_cast<float4*>(outputs + g4)      = a0;
    *reinterpret_cast<float4*>(outputs + TB + g4) = a1;
}

extern "C" void kernel_launch(void* const* d_in, const int* in_sizes, int n_in,
                              void* d_out, int out_size, void* d_ws, size_t ws_size,
                              hipStream_t stream) {
    const float* u    = (const float*)d_in[0];
    const float* rn   = (const float*)d_in[1];
    const float* inn  = (const float*)d_in[2];
    const float* Winp = (const float*)d_in[3];
    const float* Wrec = (const float*)d_in[4];
    const float* Wout = (const float*)d_in[5];

    float* states  = (float*)d_out;                          // 64*1024*1024
    float* outputs = (float*)d_out + (size_t)NN * TT * BB;   // 2*1024*1024

    latent_rnn<<<256, 256, 0, stream>>>(u, rn, inn, Winp, Wrec, states);
    out_proj<<<1024, 256, 0, stream>>>(states, Wout, outputs);
}